// Round 3
// baseline (289.391 us; speedup 1.0000x reference)
//
#include <hip/hip_runtime.h>
#include <math.h>

#define B_ROWS 16384
#define DLAT   2048
#define NTOT   (2 * B_ROWS)              // 32768 rows
#define TILE_ROWS 4
#define TILE_FLOATS (TILE_ROWS * DLAT)   // 8192 floats = 32 KB
#define NTILES (NTOT / TILE_ROWS)        // 8192 tiles
#define NBLK1  512                       // 2 blocks/CU (LDS-limited)
#define TILES_PER_BLK (NTILES / NBLK1)   // 16
#define NBLK3  128

typedef __attribute__((address_space(3))) unsigned char lds_t;
typedef const __attribute__((address_space(1))) unsigned char glb_t;

__device__ __forceinline__ void gld_lds16(const float* g, float* l) {
    __builtin_amdgcn_global_load_lds((glb_t*)(const void*)g,
                                     (lds_t*)(void*)l, 16, 0, 0);
}

// K1: async-staged GEMV. Each block: double-buffered 32KB row tiles in LDS,
// staged via global_load_lds (8 x 1KB wave-instructions per wave per tile,
// vmcnt-counted, never drained mid-loop). W lives in 32 VGPRs/thread.
__global__ __launch_bounds__(256) void k_dot_sig(
    const float* __restrict__ zi, const float* __restrict__ zj,
    const float* __restrict__ W,  const float* __restrict__ bptr,
    float* __restrict__ sp, float* __restrict__ partial)
{
    __shared__ float buf[2][TILE_FLOATS];   // 64 KB
    __shared__ float wsum[4];

    const int lane = threadIdx.x & 63;
    const int wv   = threadIdx.x >> 6;

    // W -> registers (8 KB; L2-hot after first blocks)
    const float4* w4p = (const float4*)W;
    float4 w[8];
    #pragma unroll
    for (int i = 0; i < 8; ++i) w[i] = w4p[i * 64 + lane];
    const float bias = bptr[0];

    const int t0 = blockIdx.x * TILES_PER_BLK;

    auto stage = [&](int bi, int tile) {
        const int r = tile * TILE_ROWS;
        const float* gb = (r < B_ROWS) ? zi + (size_t)r * DLAT
                                       : zj + (size_t)(r - B_ROWS) * DLAT;
        const float* g = gb + wv * 2048 + lane * 4;   // float offsets
        float* l = &buf[bi][wv * 2048];               // wave-uniform LDS base
        #pragma unroll
        for (int i = 0; i < 8; ++i)
            gld_lds16(g + i * 256, l + i * 256);      // 1 KB per instr
    };

    stage(0, t0);

    float bsum = 0.0f;

    for (int t = 0; t < TILES_PER_BLK; ++t) {
        const int cur = t & 1;
        if (t + 1 < TILES_PER_BLK) {
            stage(cur ^ 1, t0 + t + 1);                       // prefetch next
            asm volatile("s_waitcnt vmcnt(8)" ::: "memory");  // cur tile done
        } else {
            asm volatile("s_waitcnt vmcnt(0)" ::: "memory");
        }
        __builtin_amdgcn_s_barrier();       // all waves' staging visible
        asm volatile("" ::: "memory");

        // wave wv owns row wv of the tile: 8 x ds_read_b128 + FMA
        const float4* rowp = (const float4*)&buf[cur][wv * 2048];
        float acc = 0.0f;
        #pragma unroll
        for (int i = 0; i < 8; ++i) {
            float4 z = rowp[i * 64 + lane];
            acc += z.x * w[i].x + z.y * w[i].y + z.z * w[i].z + z.w * w[i].w;
        }
        #pragma unroll
        for (int off = 32; off > 0; off >>= 1)
            acc += __shfl_xor(acc, off, 64);

        if (lane == 0) {
            int row = (t0 + t) * TILE_ROWS + wv;
            float s = 1.0f / (1.0f + expf(-(acc + bias)));
            sp[row] = s;
            bsum += s;
        }
        asm volatile("" ::: "memory");
        __builtin_amdgcn_s_barrier();       // protect buf[cur] before re-stage
    }

    if (lane == 0) wsum[wv] = bsum;
    __syncthreads();
    if (threadIdx.x == 0)
        partial[blockIdx.x] = (wsum[0] + wsum[1]) + (wsum[2] + wsum[3]);
}

// K2: total_s_pos = sum of 512 block partials.
__global__ __launch_bounds__(512) void k_total(
    const float* __restrict__ partial, float* __restrict__ total)
{
    __shared__ float red[512];
    const int t = threadIdx.x;
    red[t] = partial[t];
    __syncthreads();
    #pragma unroll
    for (int s = 256; s > 0; s >>= 1) {
        if (t < s) red[t] += red[t + s];
        __syncthreads();
    }
    if (t == 0) total[0] = red[0];
}

// K3: per-row loss, 128 blocks x 256 threads.
__global__ __launch_bounds__(256) void k_loss(
    const float* __restrict__ sp, const float* __restrict__ total,
    float* __restrict__ lp)
{
    const int t = threadIdx.x;
    const int r = blockIdx.x * 256 + t;

    const float tot = total[0];
    const float c1  = 0.5f / (((float)NTOT - 2.0f) * 0.7f);
    const float c2  = (0.5f * 0.3f) / (2.0f * 0.7f);

    float S2  = sp[r] + sp[r ^ B_ROWS];
    float pos = 0.25f * (2.0f - S2);
    float neg = c1 * (tot - S2) - c2 * S2;
    float l   = (neg < 0.0f) ? -neg : (pos + neg);

    __shared__ float red[256];
    red[t] = l;
    __syncthreads();
    #pragma unroll
    for (int s = 128; s > 0; s >>= 1) {
        if (t < s) red[t] += red[t + s];
        __syncthreads();
    }
    if (t == 0) lp[blockIdx.x] = red[0];
}

// K4: mean over 128 loss partials.
__global__ __launch_bounds__(128) void k_mean(
    const float* __restrict__ lp, float* __restrict__ out)
{
    __shared__ float red[128];
    const int t = threadIdx.x;
    red[t] = lp[t];
    __syncthreads();
    #pragma unroll
    for (int s = 64; s > 0; s >>= 1) {
        if (t < s) red[t] += red[t + s];
        __syncthreads();
    }
    if (t == 0) out[0] = red[0] / (float)NTOT;
}

extern "C" void kernel_launch(void* const* d_in, const int* in_sizes, int n_in,
                              void* d_out, int out_size, void* d_ws, size_t ws_size,
                              hipStream_t stream) {
    const float* zi = (const float*)d_in[0];
    const float* zj = (const float*)d_in[1];
    const float* W  = (const float*)d_in[2];
    const float* b  = (const float*)d_in[3];

    float* sp      = (float*)d_ws;        // NTOT floats
    float* partial = sp + NTOT;           // NBLK1 floats
    float* lp      = partial + NBLK1;     // NBLK3 floats
    float* total   = lp + NBLK3;          // 1 float
    float* out     = (float*)d_out;

    k_dot_sig<<<NBLK1, 256, 0, stream>>>(zi, zj, W, b, sp, partial);
    k_total <<<1, 512, 0, stream>>>(partial, total);
    k_loss  <<<NBLK3, 256, 0, stream>>>(sp, total, lp);
    k_mean  <<<1, 128, 0, stream>>>(lp, out);
}

// Round 5
// 272.216 us; speedup vs baseline: 1.0631x; 1.0631x over previous
//
#include <hip/hip_runtime.h>
#include <math.h>

#define B_ROWS 16384
#define DLAT   2048
#define NTOT   (2 * B_ROWS)     // 32768 rows
#define NBLK_H 2048             // blocks per half: 16384 rows / 8 rows-per-block
#define NPART  (2 * NBLK_H)     // 4096 partials
#define NBLK3  128

typedef float nfloat4 __attribute__((ext_vector_type(4)));  // native vec for nt builtin

// One half (16384 rows = one input tensor) per kernel. 2 rows/wave,
// 4 waves/block. Template NT: nontemporal (cache-bypass) vs regular loads —
// within-run A/B of the cache-allocation policy on the streaming read path.
template<bool NT>
__global__ __launch_bounds__(256) void k_half(
    const float* __restrict__ z, const float* __restrict__ W,
    const float* __restrict__ bptr, float* __restrict__ sp,
    float* __restrict__ partial)
{
    const int lane = threadIdx.x & 63;
    const int wv   = threadIdx.x >> 6;
    const int r0   = (blockIdx.x * 4 + wv) * 2;   // local row in [0,16384)
    const int r1   = r0 + 1;

    const nfloat4* pa = (const nfloat4*)(z + (size_t)r0 * DLAT);
    const nfloat4* pb = (const nfloat4*)(z + (size_t)r1 * DLAT);
    const nfloat4* w4 = (const nfloat4*)W;

    float aA = 0.0f, aB = 0.0f;
    #pragma unroll
    for (int i = 0; i < 8; ++i) {
        nfloat4 za, zb;
        if constexpr (NT) {
            za = __builtin_nontemporal_load(&pa[i * 64 + lane]);
            zb = __builtin_nontemporal_load(&pb[i * 64 + lane]);
        } else {
            za = pa[i * 64 + lane];
            zb = pb[i * 64 + lane];
        }
        nfloat4 w = w4[i * 64 + lane];
        aA += za.x * w.x + za.y * w.y + za.z * w.z + za.w * w.w;
        aB += zb.x * w.x + zb.y * w.y + zb.z * w.z + zb.w * w.w;
    }

    #pragma unroll
    for (int off = 32; off > 0; off >>= 1) {
        aA += __shfl_xor(aA, off, 64);
        aB += __shfl_xor(aB, off, 64);
    }

    __shared__ float s8[8];
    if (lane == 0) {
        float b  = bptr[0];
        float sA = 1.0f / (1.0f + expf(-(aA + b)));
        float sB = 1.0f / (1.0f + expf(-(aB + b)));
        sp[r0] = sA; sp[r1] = sB;
        s8[wv * 2] = sA; s8[wv * 2 + 1] = sB;
    }
    __syncthreads();
    if (threadIdx.x == 0)
        partial[blockIdx.x] = ((s8[0] + s8[1]) + (s8[2] + s8[3]))
                            + ((s8[4] + s8[5]) + (s8[6] + s8[7]));
}

// total_s_pos = sum of 4096 block partials.
__global__ __launch_bounds__(1024) void k_total(
    const float* __restrict__ partial, float* __restrict__ total)
{
    __shared__ float red[1024];
    const int t = threadIdx.x;
    float s = 0.0f;
    for (int i = t; i < NPART; i += 1024) s += partial[i];
    red[t] = s;
    __syncthreads();
    #pragma unroll
    for (int st = 512; st > 0; st >>= 1) {
        if (t < st) red[t] += red[t + st];
        __syncthreads();
    }
    if (t == 0) total[0] = red[0];
}

// per-row loss, 128 blocks x 256 threads.
__global__ __launch_bounds__(256) void k_loss(
    const float* __restrict__ sp, const float* __restrict__ total,
    float* __restrict__ lp)
{
    const int t = threadIdx.x;
    const int r = blockIdx.x * 256 + t;

    const float tot = total[0];
    const float c1  = 0.5f / (((float)NTOT - 2.0f) * 0.7f);
    const float c2  = (0.5f * 0.3f) / (2.0f * 0.7f);

    float S2  = sp[r] + sp[r ^ B_ROWS];
    float pos = 0.25f * (2.0f - S2);
    float neg = c1 * (tot - S2) - c2 * S2;
    float l   = (neg < 0.0f) ? -neg : (pos + neg);

    __shared__ float red[256];
    red[t] = l;
    __syncthreads();
    #pragma unroll
    for (int st = 128; st > 0; st >>= 1) {
        if (t < st) red[t] += red[t + st];
        __syncthreads();
    }
    if (t == 0) lp[blockIdx.x] = red[0];
}

// mean over 128 loss partials.
__global__ __launch_bounds__(128) void k_mean(
    const float* __restrict__ lp, float* __restrict__ out)
{
    __shared__ float red[128];
    const int t = threadIdx.x;
    red[t] = lp[t];
    __syncthreads();
    #pragma unroll
    for (int st = 64; st > 0; st >>= 1) {
        if (t < st) red[t] += red[t + st];
        __syncthreads();
    }
    if (t == 0) out[0] = red[0] / (float)NTOT;
}

extern "C" void kernel_launch(void* const* d_in, const int* in_sizes, int n_in,
                              void* d_out, int out_size, void* d_ws, size_t ws_size,
                              hipStream_t stream) {
    const float* zi = (const float*)d_in[0];
    const float* zj = (const float*)d_in[1];
    const float* W  = (const float*)d_in[2];
    const float* b  = (const float*)d_in[3];

    float* sp      = (float*)d_ws;        // NTOT floats
    float* partial = sp + NTOT;           // NPART floats
    float* lp      = partial + NPART;     // NBLK3 floats
    float* total   = lp + NBLK3;          // 1 float
    float* out     = (float*)d_out;

    // A/B: zi half with nontemporal loads, zj half with regular loads.
    k_half<true ><<<NBLK_H, 256, 0, stream>>>(zi, W, b, sp,          partial);
    k_half<false><<<NBLK_H, 256, 0, stream>>>(zj, W, b, sp + B_ROWS, partial + NBLK_H);
    k_total<<<1, 1024, 0, stream>>>(partial, total);
    k_loss <<<NBLK3, 256, 0, stream>>>(sp, total, lp);
    k_mean <<<1, 128, 0, stream>>>(lp, out);
}